// Round 3
// baseline (218.786 us; speedup 1.0000x reference)
//
#include <hip/hip_runtime.h>

// FindInstancePeaks: fused conv backbone + global peak finding.
// crops (128,192,192,1) f32 -> conv1 3x3 s2 SAME (1->32) + relu
//                          -> conv2 3x3 s1 SAME (32->17) = cms (128,96,96,17)
// -> per (b,n): argmax over 96x96, quarter-pixel sign refine, *2, NaN<0.2.
//
// R11: force the intended instruction stream (R10 measured ~24k VALU
// insts/thread vs ~11k counted -- compiler overhead or scalarized v2f):
//  (1) conv2 inner loop = inline-asm v_pk_fma_f32, weight pair as SGPR
//      pair ("s" constraint, uniform s_load, zero v_movs), h broadcast
//      pairs built once per (cl,ky) and reused across the 3 kx taps.
//  (2) conv1 per-pixel state {in_off, out_off, validf} precomputed once
//      before the g-loop: per group it is 9 imm-offset ds_read_b32 +
//      18 fmaf + max/mul + 2 ds_write, no divisions/bounds logic.
//  (3) accumulation order unchanged (cl outer, k ascending, q ascending)
//      -> bit-exact output preserved.
// Grid/LDS/launch_bounds unchanged from R10 (1536 blocks = exact 6/CU).

#define NCH 17
#define C1 32
#define TW 24           // tile width
#define TH 32           // tile height
#define HT_W 26         // h cols needed (TW+2)
#define HT_H 34         // h rows needed (TH+2)
#define HSTR 28         // s_h col stride
#define IN_W 53         // input patch cols: 2*HT_W+1
#define IN_H 69         // input patch rows: 2*HT_H+1
#define CG 2            // conv1 channels per group
#define NG 16           // groups
#define NHPX (HT_H * HT_W)   // 884 h-pixels per block

typedef float v2f __attribute__((ext_vector_type(2)));

__device__ __forceinline__ unsigned long long pack_key(float v, unsigned flat) {
    unsigned ub = __float_as_uint(v);
    ub = (ub & 0x80000000u) ? ~ub : (ub | 0x80000000u);   // monotone float->uint
    return ((unsigned long long)ub << 32) | (unsigned)(~flat); // ~flat: ties -> lowest idx
}

__global__ __launch_bounds__(256, 6) void conv_peaks_kernel(
    const float* __restrict__ crops, const float* __restrict__ W1g,
    const float* __restrict__ b1g, const float* __restrict__ W2g,
    const float* __restrict__ b2g, unsigned long long* __restrict__ peaks) {
    __shared__ float s_in[IN_H * IN_W];                      // 14628 B
    __shared__ __align__(16) float s_h[CG * HT_H * HSTR];    // 7616 B

    const int t = threadIdx.x;
    const int b = blockIdx.y;
    const int ty0 = (blockIdx.x >> 2) * TH;   // 0,32,64
    const int tx0 = (blockIdx.x & 3) * TW;    // 0,24,48,72
    const int iy0 = 2 * ty0 - 2;
    const int ix0 = 2 * tx0 - 2;
    const float* cb = crops + b * 192 * 192;

    // --- stage input patch (zero-padded at image borders) ---
    for (int p = t; p < IN_H * IN_W; p += 256) {
        int r = p / IN_W, cc = p - r * IN_W;
        int iy = iy0 + r, ix = ix0 + cc;
        float v = 0.f;
        if (iy >= 0 && ix >= 0 && iy < 192 && ix < 192) v = cb[iy * 192 + ix];
        s_in[p] = v;
    }

    // --- precompute conv1 per-pixel state (group-invariant) ---
    // pixels p = t, t+256, t+512 always live; p = t+768 live iff t < 116.
    int in_off[4], out_off[4];
    float vf[4];
#pragma unroll
    for (int i = 0; i < 4; ++i) {
        int p = t + i * 256;
        int r = p / HT_W, cc = p - r * HT_W;
        int hy = ty0 - 1 + r, hx = tx0 - 1 + cc;
        bool valid = (hy >= 0) && (hy < 96) && (hx >= 0) && (hx < 96);
        vf[i] = valid ? 1.f : 0.f;
        in_off[i] = 2 * r * IN_W + 2 * cc;
        out_off[i] = r * HSTR + cc;
    }

    // thread -> 3 contiguous pixels: row ly, cols lx0..lx0+2
    const int ly = t >> 3;            // 0..31
    const int lx0 = (t & 7) * 3;      // 0,3,...,21
    v2f acc2[8][3];                   // channel pairs (2m, 2m+1)
    float acc1[3];                    // channel 16
#pragma unroll
    for (int m = 0; m < 8; ++m)
#pragma unroll
        for (int p = 0; p < 3; ++p) acc2[m][p] = (v2f)(0.f);
#pragma unroll
    for (int p = 0; p < 3; ++p) acc1[p] = 0.f;

#pragma unroll 1
    for (int g = 0; g < NG; ++g) {
        __syncthreads();   // prev conv2 reads / staging done before overwrite

        // conv1 + relu for this group's 2 channels (c0 = 2g, c1 = 2g+1)
        {
            const float b10 = b1g[2 * g], b11 = b1g[2 * g + 1];
            float w10[9], w11[9];
#pragma unroll
            for (int q = 0; q < 9; ++q) {
                w10[q] = W1g[q * C1 + 2 * g];
                w11[q] = W1g[q * C1 + 2 * g + 1];
            }
#pragma unroll
            for (int i = 0; i < 4; ++i) {
                if (i < 3 || t < NHPX - 768) {
                    const float* ip = s_in + in_off[i];
                    float in9[9];
#pragma unroll
                    for (int qy = 0; qy < 3; ++qy)
#pragma unroll
                        for (int qx = 0; qx < 3; ++qx)
                            in9[qy * 3 + qx] = ip[qy * IN_W + qx];
                    float a0 = b10, a1 = b11;
#pragma unroll
                    for (int q = 0; q < 9; ++q) {
                        a0 = fmaf(in9[q], w10[q], a0);
                        a1 = fmaf(in9[q], w11[q], a1);
                    }
                    a0 = fmaxf(a0, 0.f) * vf[i];
                    a1 = fmaxf(a1, 0.f) * vf[i];
                    s_h[out_off[i]] = a0;
                    s_h[HT_H * HSTR + out_off[i]] = a1;
                }
            }
        }
        __syncthreads();

        // conv2 partial: per cl, per ky: load 5 h floats (b32, imm offs),
        // build 5 broadcast pairs once, then per kx: 8 v_pk_fma_f32
        // (weights = SGPR pairs, zero movs) x 3 px + scalar fma for ch16.
        // k = 3*ky + kx ascends 0..8 -> accumulation order == R10.
#pragma unroll
        for (int cl = 0; cl < CG; ++cl) {
            const int c = g * CG + cl;
            const float* hp = s_h + cl * (HT_H * HSTR) + ly * HSTR + lx0;
#pragma unroll
            for (int ky = 0; ky < 3; ++ky) {
                float hr[5];
#pragma unroll
                for (int j = 0; j < 5; ++j) hr[j] = hp[ky * HSTR + j];
                v2f hb[5];
#pragma unroll
                for (int j = 0; j < 5; ++j) hb[j] = (v2f){hr[j], hr[j]};
#pragma unroll
                for (int kx = 0; kx < 3; ++kx) {
                    const int k = ky * 3 + kx;
                    const float* wb = W2g + (k * C1 + c) * NCH;  // uniform
                    float w[NCH];
#pragma unroll
                    for (int n = 0; n < NCH; ++n) w[n] = wb[n];  // s_load(s)
#pragma unroll
                    for (int p = 0; p < 3; ++p) {
#pragma unroll
                        for (int m = 0; m < 8; ++m) {
                            v2f wp = (v2f){w[2 * m], w[2 * m + 1]};
                            asm("v_pk_fma_f32 %0, %1, %2, %0"
                                : "+v"(acc2[m][p])
                                : "v"(hb[kx + p]), "s"(wp));
                        }
                        acc1[p] = fmaf(hr[kx + p], w[16], acc1[p]);
                    }
                }
            }
        }
    }

    // --- per-channel argmax: in-thread max over 3 px, then wave reduce ---
    const int yg = ty0 + ly, xg = tx0 + lx0;
    const int lane = t & 63;
#pragma unroll
    for (int n = 0; n < NCH; ++n) {
        const float bb = b2g[n];
        float v_[3];
#pragma unroll
        for (int p = 0; p < 3; ++p)
            v_[p] = ((n < 16) ? acc2[n >> 1][p][n & 1] : acc1[p]) + bb;
        unsigned long long pk = pack_key(v_[0], (unsigned)(yg * 96 + xg));
#pragma unroll
        for (int p = 1; p < 3; ++p) {
            unsigned long long o = pack_key(v_[p], (unsigned)(yg * 96 + xg + p));
            if (o > pk) pk = o;
        }
#pragma unroll
        for (int off = 32; off; off >>= 1) {
            unsigned long long o = __shfl_down(pk, off, 64);
            if (o > pk) pk = o;
        }
        if (lane == 0) atomicMax(&peaks[b * NCH + n], pk);
    }
}

// One 64-lane wave per (b,n): decode peak, recompute 4 clipped neighbor cms
// values (b2 cancels in the sign differences), emit (x,y,val).
__global__ __launch_bounds__(64) void refine_kernel(
    const float* __restrict__ crops, const float* __restrict__ W1g,
    const float* __restrict__ b1g, const float* __restrict__ W2g,
    const unsigned long long* __restrict__ peaks, float* __restrict__ out) {
    const int bn = blockIdx.x;          // 0..128*17-1
    const int b = bn / NCH, n = bn % NCH;
    const int lane = threadIdx.x;

    unsigned long long pk = peaks[bn];
    unsigned key = (unsigned)(pk >> 32);
    unsigned fbits = (key & 0x80000000u) ? (key ^ 0x80000000u) : ~key;
    float val = __uint_as_float(fbits);
    int flat = (int)(~(unsigned)(pk & 0xffffffffu));
    int yi = flat / 96, xi = flat - yi * 96;

    // neighbor j: 0:(yi,xi+1) 1:(yi,xi-1) 2:(yi+1,xi) 3:(yi-1,xi), clipped
    const int j = lane >> 4;
    int yy = yi + ((j == 2) ? 1 : 0) - ((j == 3) ? 1 : 0);
    int xx = xi + ((j == 0) ? 1 : 0) - ((j == 1) ? 1 : 0);
    yy = min(max(yy, 0), 95);
    xx = min(max(xx, 0), 95);

    // hoist 7x7 crops patch: rows 2yy-2..2yy+4, cols 2xx-2..2xx+4
    const float* cb = crops + b * 192 * 192;
    float pat[7][7];
#pragma unroll
    for (int r = 0; r < 7; ++r) {
        int iy = 2 * yy - 2 + r;
#pragma unroll
        for (int s = 0; s < 7; ++s) {
            int ix = 2 * xx - 2 + s;
            pat[r][s] = (iy >= 0 && iy < 192 && ix >= 0 && ix < 192)
                            ? cb[iy * 192 + ix] : 0.f;
        }
    }

    float part = 0.f;
#pragma unroll
    for (int ci = 0; ci < 2; ++ci) {
        const int c = (lane & 15) + ci * 16;
        const float bias = b1g[c];
        float w1[9];
#pragma unroll
        for (int q = 0; q < 9; ++q) w1[q] = W1g[q * C1 + c];
#pragma unroll
        for (int dy = 0; dy < 3; ++dy) {
#pragma unroll
            for (int dx = 0; dx < 3; ++dx) {
                int hy = yy - 1 + dy, hx = xx - 1 + dx;
                if (hy >= 0 && hy < 96 && hx >= 0 && hx < 96) {
                    float a = bias;
#pragma unroll
                    for (int qy = 0; qy < 3; ++qy)
#pragma unroll
                        for (int qx = 0; qx < 3; ++qx)
                            a = fmaf(pat[2 * dy + qy][2 * dx + qx],
                                     w1[qy * 3 + qx], a);
                    float hval = fmaxf(a, 0.f);
                    part = fmaf(hval, W2g[((dy * 3 + dx) * C1 + c) * NCH + n], part);
                }
            }
        }
    }
    // sum the 16 lanes of each neighbor group
    for (int off = 8; off; off >>= 1) part += __shfl_down(part, off, 16);
    float g0 = __shfl(part, 0, 64);
    float g1 = __shfl(part, 16, 64);
    float g2 = __shfl(part, 32, 64);
    float g3 = __shfl(part, 48, 64);

    if (lane == 0) {
        float d0 = g0 - g1, d1 = g2 - g3;
        float sx = (d0 > 0.f) ? 1.f : ((d0 < 0.f) ? -1.f : 0.f);
        float sy = (d1 > 0.f) ? 1.f : ((d1 < 0.f) ? -1.f : 0.f);
        float px = ((float)xi + 0.25f * sx) * 2.f;
        float py = ((float)yi + 0.25f * sy) * 2.f;
        if (!(val >= 0.2f)) {
            px = __int_as_float(0x7fc00000);
            py = __int_as_float(0x7fc00000);
        }
        out[bn * 3 + 0] = px;
        out[bn * 3 + 1] = py;
        out[bn * 3 + 2] = val;
    }
}

extern "C" void kernel_launch(void* const* d_in, const int* in_sizes, int n_in,
                              void* d_out, int out_size, void* d_ws, size_t ws_size,
                              hipStream_t stream) {
    const float* crops = (const float*)d_in[0];
    const float* W1 = (const float*)d_in[1];
    const float* b1 = (const float*)d_in[2];
    const float* W2 = (const float*)d_in[3];
    const float* b2 = (const float*)d_in[4];
    float* out = (float*)d_out;
    unsigned long long* peaks = (unsigned long long*)d_ws;

    hipMemsetAsync(d_ws, 0, 128 * NCH * sizeof(unsigned long long), stream);

    dim3 gridB(12, 128);  // 4x3 tiles of 24x32 over 96x96, per image
    conv_peaks_kernel<<<gridB, 256, 0, stream>>>(crops, W1, b1, W2, b2, peaks);
    refine_kernel<<<128 * NCH, 64, 0, stream>>>(crops, W1, b1, W2, peaks, out);
}